// Round 7
// baseline (2732.222 us; speedup 1.0000x reference)
//
#include <hip/hip_runtime.h>

// ---------------- problem constants ----------------
constexpr int B = 64, L = 512, E = 256, H = 512;
constexpr int ROWS = 4 * H;      // 2048 gate-rows (unit*4 + gate interleave)
constexpr int K    = E + H;      // 768
constexpr int K4   = K / 4;      // 192

// ---------------- ws layout (in floats) ----------------
constexpr size_t OFF_WT4   = 0;
constexpr size_t SZ_WT4    = (size_t)K4 * ROWS * 4;     // float4[K4][ROWS]
constexpr size_t OFF_BI    = OFF_WT4 + SZ_WT4;          // interleaved biases [ROWS]
constexpr size_t SZ_BI     = ROWS;
constexpr size_t OFF_H2    = OFF_BI + SZ_BI;            // TAGGED h dbuf [2][B][H] x (val,tag)
constexpr size_t SZ_H2     = (size_t)2 * B * H * 2;     // in floats (u64 per element)
constexpr size_t OFF_REP   = OFF_H2 + SZ_H2;            // rep accumulator [B][H]
constexpr size_t SZ_REP    = (size_t)B * H;
constexpr size_t WS_FLOATS = OFF_REP + SZ_REP;

// ---------------- prep: transpose + interleave weights, invalidate h tags ----------------
__global__ __launch_bounds__(256) void prep_weights(
    const float* __restrict__ Wf, const float* __restrict__ Wi,
    const float* __restrict__ Wc, const float* __restrict__ Wo,
    const float* __restrict__ bf, const float* __restrict__ bi,
    const float* __restrict__ bc, const float* __restrict__ bo,
    float* __restrict__ ws)
{
    float* WT4 = ws + OFF_WT4;
    float* bI  = ws + OFF_BI;
    int idx = blockIdx.x * 256 + threadIdx.x;            // 65536 threads
    const float* Ws[4] = {Wf, Wi, Wc, Wo};
    #pragma unroll
    for (int j = 0; j < 6; ++j) {
        int item = idx + j * 65536;                      // [0, 393216)
        int k4   = item >> 11;                           // /2048
        int row  = item & 2047;
        int unit = row >> 2, gate = row & 3;
        const float* W = Ws[gate];
        float4 v = *(const float4*)(W + (size_t)unit * K + (size_t)k4 * 4);
        *(float4*)(WT4 + ((size_t)k4 * ROWS + row) * 4) = v;
    }
    if (idx < ROWS) {
        int unit = idx >> 2, gate = idx & 3;
        const float* bs[4] = {bf, bi, bc, bo};
        bI[idx] = bs[gate][unit];
    }
    // zero all tags (tag 0 matches no want >= 2); end-of-dispatch L2 writeback makes
    // these visible to persist's sc-bypass loads (validated R2..R6).
    ((unsigned long long*)(ws + OFF_H2))[idx] = 0ull;    // 2*B*H = 65536 u64 exactly
}

// ---------------- persistent LSTM kernel ----------------
// grid 256 = 32 row-groups x 8 seq-groups; bid = rg*8 + sg.
// block 256 thr = 4 waves; wave w, lane l: rl8 = l&7 (rows rg*64+8*rl8..+7),
// qq = l>>3 (k-chunk m = w*8+qq, 0..31).
//
// R7 GEMV geometry (3rd application of the R4/R5-validated LDS return-bus lever):
// 8 rows/lane x 6 k4 -- one ds_read_b128 broadcast feeds 32 FMAs. E+H broadcast
// reads drop 384 -> 192 b128 per CU per step. To keep part2 at 32 KB (64 KB LDS
// cap), a DPP row_ror:8 butterfly (lane l <-> l^8, VALU pipe) pre-sums qq-pairs
// before the partial write -> 16 m-slices per row, reduce identical to R5.
// Broadcast banks: 8 qq-groups read (m+32jj)*16B, 16B apart -> 32 banks, 8-way
// same-address broadcast = conflict-free.
//
// REGISTER RULE (R1 failure): weights live in ONE wreg[48] float4 array with
// constant indices (E=[0..15], H=[16..47]) -> AGPR promotion; never split it.
//
// Cross-block protocol = tagged scheme (R3..R5, R6 half-split reverted as
// neutral): each h element is an 8-byte atomic (f32 value, u32 tag); producers
// store (h, t+2) with one relaxed agent-scope store; consumers' staging load IS
// the poll (retry until __all(tags == t+1)). WAR on the dbuf: per-step
// all-gather bounds inter-block skew < 1 step; tags self-detect staleness.
__global__ __launch_bounds__(256, 1) void lstm_persist(
    float* __restrict__ ws,
    const int* __restrict__ x, const int* __restrict__ mask,
    const float* __restrict__ embed)
{
    __shared__ float emb_lds[2][8][E];                   // 16 KB dbuf (local gather)
    __shared__ float h_lds[8 * H];                       // 16 KB
    __shared__ float part2_lds[8 * 16 * 64];             // 32 KB: [s8][p=0..16][row]

    const int bid = blockIdx.x;
    const int rg  = bid >> 3, sg = bid & 7;
    const int tid = threadIdx.x;
    const int w   = tid >> 6, l = tid & 63;
    const int rl8 = l & 7, qq = l >> 3;                  // GEMV mapping
    const int m   = w * 8 + qq;                          // k-chunk 0..31
    const int seq_base = sg * 8;
    const int gate = l & 3, qlane = l >> 2;              // reduce: lane l owns row rg*64+l

    const float4* WT4 = (const float4*)(ws + OFF_WT4);
    const float*  bI  = ws + OFF_BI;
    unsigned long long* h2 = (unsigned long long*)(ws + OFF_H2);
    float* repg = ws + OFF_REP;

    // ---- stationary weights: ONE array, const indices (AGPR promotion!)
    // E: wreg[r*2+jj] = WT4[m+32jj][rowA+r]; H: wreg[16+r*4+jj] = WT4[64+m+32jj][rowA+r]
    float4 wreg[48];
    {
        const int rowA = rg * 64 + rl8 * 8;
        #pragma unroll
        for (int jj = 0; jj < 2; ++jj)
            #pragma unroll
            for (int r = 0; r < 8; ++r)
                wreg[r * 2 + jj] = WT4[(size_t)(m + 32 * jj) * ROWS + rowA + r];
        #pragma unroll
        for (int jj = 0; jj < 4; ++jj)
            #pragma unroll
            for (int r = 0; r < 8; ++r)
                wreg[16 + r * 4 + jj] = WT4[(size_t)(64 + m + 32 * jj) * ROWS + rowA + r];
    }
    const float breg = bI[rg * 64 + l];                  // bias for the REDUCE row

    // ---- per-owner-lane state (lanes with gate==0), 2 phases: seqs w and w+4
    float c0 = 0.f, c1 = 0.f, h0 = 0.f, h1 = 0.f, r0 = 0.f, r1 = 0.f;

    const int sl = tid >> 5, col = (tid & 31) * 8;       // emb gather mapping

    // ---- prologue: local emb gather for t=0; h_lds = 0 (no poll at t=0)
    {
        int tok = x[(size_t)(seq_base + sl) * L + 0];
        const float* er = embed + (size_t)tok * E + col;
        *(float4*)&emb_lds[0][sl][col]     = *(const float4*)er;
        *(float4*)&emb_lds[0][sl][col + 4] = *(const float4*)(er + 4);
        #pragma unroll
        for (int i = 0; i < 16; ++i) h_lds[tid + i * 256] = 0.f;
    }
    __syncthreads();

    // ---- main recurrence: 2 barriers per step, zero flags, zero fences
    for (int t = 0; t < L; ++t) {
        const int cur = t & 1, nxt = cur ^ 1;
        const unsigned long long* c2c = h2 + (size_t)cur * B * H + (size_t)seq_base * H;
        unsigned long long*       c2n = h2 + (size_t)nxt * B * H + (size_t)seq_base * H;

        // (a) local emb prefetch for t+1 (plain cached loads, read-only data)
        float4 e0, e1;
        const bool pf = (t + 1) < L;
        if (pf) {
            int tok = x[(size_t)(seq_base + sl) * L + (t + 1)];
            const float* er = embed + (size_t)tok * E + col;
            e0 = *(const float4*)er;
            e1 = *(const float4*)(er + 4);
        }

        // (b) issue tagged h loads (16 u64/thread); tag check deferred past E-GEMV
        unsigned long long hv[16];
        if (t > 0) {
            #pragma unroll
            for (int i = 0; i < 8; ++i) {
                hv[2 * i]     = __hip_atomic_load(&c2c[i * 512 + tid * 2],
                                    __ATOMIC_RELAXED, __HIP_MEMORY_SCOPE_AGENT);
                hv[2 * i + 1] = __hip_atomic_load(&c2c[i * 512 + tid * 2 + 1],
                                    __ATOMIC_RELAXED, __HIP_MEMORY_SCOPE_AGENT);
            }
        }

        // (c) E-GEMV while tagged loads fly: 512 FMAs, 1 b128 per 32 FMAs
        float acc[8][8];
        #pragma unroll
        for (int r = 0; r < 8; ++r)
            #pragma unroll
            for (int s8 = 0; s8 < 8; ++s8) acc[r][s8] = 0.f;
        #pragma unroll
        for (int jj = 0; jj < 2; ++jj) {
            const int off = (m + 32 * jj) * 4;
            #pragma unroll
            for (int s8 = 0; s8 < 8; ++s8) {
                float4 c4 = *(const float4*)&emb_lds[cur][s8][off];
                #pragma unroll
                for (int r = 0; r < 8; ++r) {
                    float4 wv = wreg[r * 2 + jj];
                    acc[r][s8] = fmaf(wv.x, c4.x, acc[r][s8]);
                    acc[r][s8] = fmaf(wv.y, c4.y, acc[r][s8]);
                    acc[r][s8] = fmaf(wv.z, c4.z, acc[r][s8]);
                    acc[r][s8] = fmaf(wv.w, c4.w, acc[r][s8]);
                }
            }
        }

        // (d) verify tags (retry rare), land h into LDS
        if (t > 0) {
            const unsigned int want = (unsigned int)(t + 1);
            int guard = 0;
            for (;;) {
                bool ok = true;
                #pragma unroll
                for (int i = 0; i < 16; ++i)
                    ok &= ((unsigned int)(hv[i] >> 32) == want);
                if (__all(ok) || ++guard > (1 << 20)) break;
                __builtin_amdgcn_s_sleep(2);
                #pragma unroll
                for (int i = 0; i < 8; ++i) {
                    hv[2 * i]     = __hip_atomic_load(&c2c[i * 512 + tid * 2],
                                        __ATOMIC_RELAXED, __HIP_MEMORY_SCOPE_AGENT);
                    hv[2 * i + 1] = __hip_atomic_load(&c2c[i * 512 + tid * 2 + 1],
                                        __ATOMIC_RELAXED, __HIP_MEMORY_SCOPE_AGENT);
                }
            }
            #pragma unroll
            for (int i = 0; i < 8; ++i)
                *(float2*)&h_lds[i * 512 + tid * 2] = make_float2(
                    __uint_as_float((unsigned int)hv[2 * i]),
                    __uint_as_float((unsigned int)hv[2 * i + 1]));
        }

        // (e) land emb prefetch
        if (pf) {
            *(float4*)&emb_lds[nxt][sl][col]     = e0;
            *(float4*)&emb_lds[nxt][sl][col + 4] = e1;
        }
        __syncthreads();                                 // S1: h_lds/emb ready

        // (f) H-GEMV: 1024 FMAs, 1 b128 per 32 FMAs
        #pragma unroll
        for (int jj = 0; jj < 4; ++jj) {
            const int off = (m + 32 * jj) * 4;
            #pragma unroll
            for (int s8 = 0; s8 < 8; ++s8) {
                float4 c4 = *(const float4*)&h_lds[s8 * 512 + off];
                #pragma unroll
                for (int r = 0; r < 8; ++r) {
                    float4 wv = wreg[16 + r * 4 + jj];
                    acc[r][s8] = fmaf(wv.x, c4.x, acc[r][s8]);
                    acc[r][s8] = fmaf(wv.y, c4.y, acc[r][s8]);
                    acc[r][s8] = fmaf(wv.z, c4.z, acc[r][s8]);
                    acc[r][s8] = fmaf(wv.w, c4.w, acc[r][s8]);
                }
            }
        }

        // (f2) DPP butterfly over qq-pairs (lane l <-> l^8, row_ror:8 = VALU pipe):
        // both lanes end with the pair sum; even-qq lanes write the partials.
        #pragma unroll
        for (int r = 0; r < 8; ++r)
            #pragma unroll
            for (int s8 = 0; s8 < 8; ++s8) {
                int a_ = __float_as_int(acc[r][s8]);
                float o = __int_as_float(
                    __builtin_amdgcn_mov_dpp(a_, 0x128, 0xF, 0xF, true)); // row_ror:8
                acc[r][s8] += o;
            }
        if ((qq & 1) == 0) {
            const int p = w * 4 + (qq >> 1);             // 0..15
            #pragma unroll
            for (int s8 = 0; s8 < 8; ++s8) {
                const int base = (s8 * 16 + p) * 64 + rl8 * 8;
                *(float4*)&part2_lds[base]     = make_float4(acc[0][s8], acc[1][s8],
                                                             acc[2][s8], acc[3][s8]);
                *(float4*)&part2_lds[base + 4] = make_float4(acc[4][s8], acc[5][s8],
                                                             acc[6][s8], acc[7][s8]);
            }
        }
        __syncthreads();                                 // S2

        // (g) reduce 16 p-slices, activations (DPP quad-broadcast), c/h update
        #pragma unroll
        for (int p = 0; p < 2; ++p) {
            int s8 = p * 4 + w;
            float a = breg;
            #pragma unroll
            for (int mm = 0; mm < 16; ++mm)
                a += part2_lds[(s8 * 16 + mm) * 64 + l];
            float act = (gate == 2) ? tanhf(a) : 1.f / (1.f + expf(-a));
            int ab = __float_as_int(act);
            float fg = __int_as_float(__builtin_amdgcn_mov_dpp(ab, 0x00, 0xF, 0xF, true));
            float ig = __int_as_float(__builtin_amdgcn_mov_dpp(ab, 0x55, 0xF, 0xF, true));
            float cg = __int_as_float(__builtin_amdgcn_mov_dpp(ab, 0xAA, 0xF, 0xF, true));
            float og = __int_as_float(__builtin_amdgcn_mov_dpp(ab, 0xFF, 0xF, 0xF, true));
            if (gate == 0) {
                float& cr = p ? c1 : c0;
                float& hr = p ? h1 : h0;
                float& rr = p ? r1 : r0;
                cr = fg * cr + ig * cg;                  // c not mask-blended (matches ref)
                float hn = og * tanhf(cr);
                int seq = seq_base + s8;
                float mk = (mask[(size_t)seq * L + t] != 0) ? 1.f : 0.f;
                float h = hn * mk + hr * (1.f - mk);
                hr = h;
                // single 8B atomic carries value AND readiness -> no release needed
                unsigned long long p64 = (((unsigned long long)(unsigned int)(t + 2)) << 32)
                                       | (unsigned long long)__float_as_uint(h);
                __hip_atomic_store(&c2n[(size_t)s8 * H + rg * 16 + qlane],
                                   p64, __ATOMIC_RELAXED, __HIP_MEMORY_SCOPE_AGENT);
                rr += h * mk;
            }
        }
        // NO S3: next iteration's tag check is the only consumer-side gate.
    }

    // ---- epilogue: dump rep registers (unique owner per (seq,unit))
    if (gate == 0) {
        repg[(size_t)(seq_base + w)     * H + rg * 16 + qlane] = r0;
        repg[(size_t)(seq_base + w + 4) * H + rg * 16 + qlane] = r1;
    }
}

// ---------------- final: rep mean + logits ----------------
__global__ __launch_bounds__(256) void lstm_final(
    const float* __restrict__ ws,
    const int* __restrict__ mask,
    const float* __restrict__ Wfc, const float* __restrict__ bfc,
    float* __restrict__ out)
{
    __shared__ float sred[256];
    __shared__ float srep[H];
    int s = blockIdx.x, tid = threadIdx.x;

    float dsum = 0.f;
    for (int i = tid; i < L; i += 256) dsum += (mask[(size_t)s * L + i] != 0) ? 1.f : 0.f;
    sred[tid] = dsum; __syncthreads();
    for (int off = 128; off > 0; off >>= 1) {
        if (tid < off) sred[tid] += sred[tid + off];
        __syncthreads();
    }
    float denom = fmaxf(sred[0], 1e-9f);
    __syncthreads();

    const float* repa = ws + OFF_REP + (size_t)s * H;
    for (int i = tid; i < H; i += 256) {
        float r = repa[i] / denom;
        srep[i] = r;
        out[128 + (size_t)s * H + i] = r;
    }
    __syncthreads();

    for (int c = 0; c < 2; ++c) {
        float d = 0.f;
        for (int i = tid; i < H; i += 256) d += srep[i] * Wfc[(size_t)c * H + i];
        sred[tid] = d; __syncthreads();
        for (int off = 128; off > 0; off >>= 1) {
            if (tid < off) sred[tid] += sred[tid + off];
            __syncthreads();
        }
        if (tid == 0) out[(size_t)s * 2 + c] = sred[0] + bfc[c];
        __syncthreads();
    }
}

// ---------------- host ----------------
extern "C" void kernel_launch(void* const* d_in, const int* in_sizes, int n_in,
                              void* d_out, int out_size, void* d_ws, size_t ws_size,
                              hipStream_t stream)
{
    const int*   x     = (const int*)d_in[0];
    const int*   mask  = (const int*)d_in[1];
    const float* embed = (const float*)d_in[2];
    const float* Wf = (const float*)d_in[3];  const float* bf = (const float*)d_in[4];
    const float* Wi = (const float*)d_in[5];  const float* bi = (const float*)d_in[6];
    const float* Wc = (const float*)d_in[7];  const float* bc = (const float*)d_in[8];
    const float* Wo = (const float*)d_in[9];  const float* bo = (const float*)d_in[10];
    const float* Wfc = (const float*)d_in[11]; const float* bfc = (const float*)d_in[12];
    float* out = (float*)d_out;
    float* ws  = (float*)d_ws;

    if (ws_size < WS_FLOATS * sizeof(float)) {
        return; // leave output poisoned so the failure mode is unambiguous
    }

    prep_weights<<<256, 256, 0, stream>>>(Wf, Wi, Wc, Wo, bf, bi, bc, bo, ws);
    lstm_persist<<<256, 256, 0, stream>>>(ws, x, mask, embed);
    lstm_final<<<64, 256, 0, stream>>>(ws, mask, Wfc, bfc, out);
}

// Round 8
// 1972.092 us; speedup vs baseline: 1.3854x; 1.3854x over previous
//
#include <hip/hip_runtime.h>

// ---------------- problem constants ----------------
constexpr int B = 64, L = 512, E = 256, H = 512;
constexpr int ROWS = 4 * H;      // 2048 gate-rows (unit*4 + gate interleave)
constexpr int K    = E + H;      // 768
constexpr int K4   = K / 4;      // 192

// ---------------- ws layout (in floats) ----------------
constexpr size_t OFF_WT4   = 0;
constexpr size_t SZ_WT4    = (size_t)K4 * ROWS * 4;     // float4[K4][ROWS]
constexpr size_t OFF_BI    = OFF_WT4 + SZ_WT4;          // interleaved biases [ROWS]
constexpr size_t SZ_BI     = ROWS;
constexpr size_t OFF_H2    = OFF_BI + SZ_BI;            // TAGGED h dbuf [2][B][H] x (val,tag)
constexpr size_t SZ_H2     = (size_t)2 * B * H * 2;     // in floats (u64 per element)
constexpr size_t OFF_REP   = OFF_H2 + SZ_H2;            // rep accumulator [B][H]
constexpr size_t SZ_REP    = (size_t)B * H;
constexpr size_t WS_FLOATS = OFF_REP + SZ_REP;

// ---------------- prep: transpose + interleave weights, invalidate h tags ----------------
__global__ __launch_bounds__(256) void prep_weights(
    const float* __restrict__ Wf, const float* __restrict__ Wi,
    const float* __restrict__ Wc, const float* __restrict__ Wo,
    const float* __restrict__ bf, const float* __restrict__ bi,
    const float* __restrict__ bc, const float* __restrict__ bo,
    float* __restrict__ ws)
{
    float* WT4 = ws + OFF_WT4;
    float* bI  = ws + OFF_BI;
    int idx = blockIdx.x * 256 + threadIdx.x;            // 65536 threads
    const float* Ws[4] = {Wf, Wi, Wc, Wo};
    #pragma unroll
    for (int j = 0; j < 6; ++j) {
        int item = idx + j * 65536;                      // [0, 393216)
        int k4   = item >> 11;                           // /2048
        int row  = item & 2047;
        int unit = row >> 2, gate = row & 3;
        const float* W = Ws[gate];
        float4 v = *(const float4*)(W + (size_t)unit * K + (size_t)k4 * 4);
        *(float4*)(WT4 + ((size_t)k4 * ROWS + row) * 4) = v;
    }
    if (idx < ROWS) {
        int unit = idx >> 2, gate = idx & 3;
        const float* bs[4] = {bf, bi, bc, bo};
        bI[idx] = bs[gate][unit];
    }
    // zero all tags (tag 0 matches no want >= 2); end-of-dispatch L2 writeback makes
    // these visible to persist's sc-bypass loads (validated R2..R7).
    ((unsigned long long*)(ws + OFF_H2))[idx] = 0ull;    // 2*B*H = 65536 u64 exactly
}

// ---------------- persistent LSTM kernel ----------------
// grid 256 = 32 row-groups x 8 seq-groups; bid = rg*8 + sg.
// R8: block = 512 threads = 8 WAVES -> 2 waves/SIMD resident (TLP fills LDS-latency,
// barrier-join and tag-spin gaps that 1 wave/SIMD exposed; occupancy was grid-limited).
// Per-thread work halves: 24 weight float4 (96 regs), 768 FMA/step. Must fit <=256
// regs/wave for 2/SIMD -> __launch_bounds__(512, 2). R7's 8-row geometry REVERTED
// (regressed: 5x bank conflicts); per-wave GEMV geometry is R5's validated
// 4 rows/lane x 12 k4 (1 b128 broadcast : 16 FMAs), k-space split 8 ways:
//   wave w, lane l: q = l>>4, rl = l&15; rows rg*64 + rl*4 .. +3
//   E k4 = w*8 + q + 4*jj (jj<2); H k4 = 64 + w*16 + q + 4*jj (jj<4); m = w*4+q (0..31)
// Partials: 32 m-slices won't fit 64KB LDS -> two-phase: waves 0-3 WRITE slices
// 0..15, S2, waves 4-7 RMW-ADD (slice m-16), S3, reduce 16 slices (wave w = seq w).
//
// REGISTER RULE (R1 failure): weights in ONE wreg[24] float4 array, const indices.
// Cross-block protocol = tagged scheme (R3..R5): 8-byte (f32 value, u32 tag)
// atomics; producer stores (h, t+2) relaxed agent-scope; consumer staging load IS
// the poll (retry until __all(tags == t+1)). WAR: per-step all-gather bounds skew.
__global__ __launch_bounds__(512, 2) void lstm_persist(
    float* __restrict__ ws,
    const int* __restrict__ x, const int* __restrict__ mask,
    const float* __restrict__ embed)
{
    __shared__ float emb_lds[2][8][E];                   // 16 KB dbuf (local gather)
    __shared__ float h_lds[8 * H];                       // 16 KB
    __shared__ float part2_lds[8 * 16 * 64];             // 32 KB: [s8][p=0..16][row]

    const int bid = blockIdx.x;
    const int rg  = bid >> 3, sg = bid & 7;
    const int tid = threadIdx.x;
    const int w   = tid >> 6, l = tid & 63;              // w 0..7
    const int q   = l >> 4, rl = l & 15;                 // GEMV mapping
    const int m   = w * 4 + q;                           // k-chunk 0..31
    const int seq_base = sg * 8;
    const int gate = l & 3, qlane = l >> 2;              // reduce: lane l owns row rg*64+l

    const float4* WT4 = (const float4*)(ws + OFF_WT4);
    const float*  bI  = ws + OFF_BI;
    unsigned long long* h2 = (unsigned long long*)(ws + OFF_H2);
    float* repg = ws + OFF_REP;

    // ---- stationary weights: ONE array, const indices
    // E: wreg[r*2+jj] = WT4[w*8+q+4jj][rowA+r]; H: wreg[8+r*4+jj] = WT4[64+w*16+q+4jj][rowA+r]
    float4 wreg[24];
    {
        const int rowA = rg * 64 + rl * 4;
        #pragma unroll
        for (int jj = 0; jj < 2; ++jj)
            #pragma unroll
            for (int r = 0; r < 4; ++r)
                wreg[r * 2 + jj] = WT4[(size_t)(w * 8 + q + 4 * jj) * ROWS + rowA + r];
        #pragma unroll
        for (int jj = 0; jj < 4; ++jj)
            #pragma unroll
            for (int r = 0; r < 4; ++r)
                wreg[8 + r * 4 + jj] = WT4[(size_t)(64 + w * 16 + q + 4 * jj) * ROWS + rowA + r];
    }
    const float breg = bI[rg * 64 + l];                  // bias for the REDUCE row

    // ---- per-owner-lane state (gate==0 lanes): wave w owns seq (seq_base + w)
    float c0 = 0.f, h0 = 0.f, r0 = 0.f;

    const int sl = tid >> 6, col = (tid & 63) * 4;       // emb gather: 1 float4/thread

    // ---- prologue: local emb gather for t=0; h_lds = 0 (no poll at t=0)
    {
        int tok = x[(size_t)(seq_base + sl) * L + 0];
        *(float4*)&emb_lds[0][sl][col] = *(const float4*)(embed + (size_t)tok * E + col);
        #pragma unroll
        for (int i = 0; i < 8; ++i) h_lds[tid + i * 512] = 0.f;
    }
    __syncthreads();

    // ---- main recurrence: 3 barriers per step, zero flags, zero fences
    for (int t = 0; t < L; ++t) {
        const int cur = t & 1, nxt = cur ^ 1;
        const unsigned long long* c2c = h2 + (size_t)cur * B * H + (size_t)seq_base * H;
        unsigned long long*       c2n = h2 + (size_t)nxt * B * H + (size_t)seq_base * H;

        // (a) local emb prefetch for t+1 (plain cached loads, read-only data)
        float4 e0;
        const bool pf = (t + 1) < L;
        if (pf) {
            int tok = x[(size_t)(seq_base + sl) * L + (t + 1)];
            e0 = *(const float4*)(embed + (size_t)tok * E + col);
        }

        // (b) issue tagged h loads (8 u64/thread); tag check deferred past E-GEMV
        unsigned long long hv[8];
        if (t > 0) {
            #pragma unroll
            for (int i = 0; i < 4; ++i) {
                hv[2 * i]     = __hip_atomic_load(&c2c[i * 1024 + tid * 2],
                                    __ATOMIC_RELAXED, __HIP_MEMORY_SCOPE_AGENT);
                hv[2 * i + 1] = __hip_atomic_load(&c2c[i * 1024 + tid * 2 + 1],
                                    __ATOMIC_RELAXED, __HIP_MEMORY_SCOPE_AGENT);
            }
        }

        // (c) E-GEMV while tagged loads fly: 256 FMAs, 1 b128 per 16 FMAs
        float acc[4][8];
        #pragma unroll
        for (int r = 0; r < 4; ++r)
            #pragma unroll
            for (int s8 = 0; s8 < 8; ++s8) acc[r][s8] = 0.f;
        #pragma unroll
        for (int jj = 0; jj < 2; ++jj) {
            const int off = (w * 8 + q + 4 * jj) * 4;
            #pragma unroll
            for (int s8 = 0; s8 < 8; ++s8) {
                float4 c4 = *(const float4*)&emb_lds[cur][s8][off];
                #pragma unroll
                for (int r = 0; r < 4; ++r) {
                    float4 wv = wreg[r * 2 + jj];
                    acc[r][s8] = fmaf(wv.x, c4.x, acc[r][s8]);
                    acc[r][s8] = fmaf(wv.y, c4.y, acc[r][s8]);
                    acc[r][s8] = fmaf(wv.z, c4.z, acc[r][s8]);
                    acc[r][s8] = fmaf(wv.w, c4.w, acc[r][s8]);
                }
            }
        }

        // (d) verify tags (retry rare), land h into LDS
        if (t > 0) {
            const unsigned int want = (unsigned int)(t + 1);
            int guard = 0;
            for (;;) {
                bool ok = true;
                #pragma unroll
                for (int i = 0; i < 8; ++i)
                    ok &= ((unsigned int)(hv[i] >> 32) == want);
                if (__all(ok) || ++guard > (1 << 20)) break;
                __builtin_amdgcn_s_sleep(2);
                #pragma unroll
                for (int i = 0; i < 4; ++i) {
                    hv[2 * i]     = __hip_atomic_load(&c2c[i * 1024 + tid * 2],
                                        __ATOMIC_RELAXED, __HIP_MEMORY_SCOPE_AGENT);
                    hv[2 * i + 1] = __hip_atomic_load(&c2c[i * 1024 + tid * 2 + 1],
                                        __ATOMIC_RELAXED, __HIP_MEMORY_SCOPE_AGENT);
                }
            }
            #pragma unroll
            for (int i = 0; i < 4; ++i)
                *(float2*)&h_lds[i * 1024 + tid * 2] = make_float2(
                    __uint_as_float((unsigned int)hv[2 * i]),
                    __uint_as_float((unsigned int)hv[2 * i + 1]));
        }

        // (e) land emb prefetch
        if (pf) *(float4*)&emb_lds[nxt][sl][col] = e0;
        __syncthreads();                                 // S1: h_lds/emb ready

        // (f) H-GEMV: 512 FMAs, 1 b128 per 16 FMAs
        #pragma unroll
        for (int jj = 0; jj < 4; ++jj) {
            const int off = (w * 16 + q + 4 * jj) * 4;
            #pragma unroll
            for (int s8 = 0; s8 < 8; ++s8) {
                float4 c4 = *(const float4*)&h_lds[s8 * 512 + off];
                #pragma unroll
                for (int r = 0; r < 4; ++r) {
                    float4 wv = wreg[8 + r * 4 + jj];
                    acc[r][s8] = fmaf(wv.x, c4.x, acc[r][s8]);
                    acc[r][s8] = fmaf(wv.y, c4.y, acc[r][s8]);
                    acc[r][s8] = fmaf(wv.z, c4.z, acc[r][s8]);
                    acc[r][s8] = fmaf(wv.w, c4.w, acc[r][s8]);
                }
            }
        }

        // (f2) partials, two-phase into 16 slices (32 KB):
        if (w < 4) {                                     // waves 0-3: slices m = 0..15
            #pragma unroll
            for (int s8 = 0; s8 < 8; ++s8)
                *(float4*)&part2_lds[(s8 * 16 + m) * 64 + rl * 4] =
                    make_float4(acc[0][s8], acc[1][s8], acc[2][s8], acc[3][s8]);
        }
        __syncthreads();                                 // S2
        if (w >= 4) {                                    // waves 4-7: RMW-add slice m-16
            #pragma unroll
            for (int s8 = 0; s8 < 8; ++s8) {
                float4* p = (float4*)&part2_lds[(s8 * 16 + (m - 16)) * 64 + rl * 4];
                float4 o = *p;
                o.x += acc[0][s8]; o.y += acc[1][s8];
                o.z += acc[2][s8]; o.w += acc[3][s8];
                *p = o;
            }
        }
        __syncthreads();                                 // S3

        // (g) reduce 16 p-slices (wave w owns seq w), activations, c/h update
        {
            float a = breg;
            #pragma unroll
            for (int mm = 0; mm < 16; ++mm)
                a += part2_lds[(w * 16 + mm) * 64 + l];
            float act = (gate == 2) ? tanhf(a) : 1.f / (1.f + expf(-a));
            int ab = __float_as_int(act);
            float fg = __int_as_float(__builtin_amdgcn_mov_dpp(ab, 0x00, 0xF, 0xF, true));
            float ig = __int_as_float(__builtin_amdgcn_mov_dpp(ab, 0x55, 0xF, 0xF, true));
            float cg = __int_as_float(__builtin_amdgcn_mov_dpp(ab, 0xAA, 0xF, 0xF, true));
            float og = __int_as_float(__builtin_amdgcn_mov_dpp(ab, 0xFF, 0xF, 0xF, true));
            if (gate == 0) {
                c0 = fg * c0 + ig * cg;                  // c not mask-blended (matches ref)
                float hn = og * tanhf(c0);
                int seq = seq_base + w;
                float mk = (mask[(size_t)seq * L + t] != 0) ? 1.f : 0.f;
                float h = hn * mk + h0 * (1.f - mk);
                h0 = h;
                // single 8B atomic carries value AND readiness -> no release needed
                unsigned long long p64 = (((unsigned long long)(unsigned int)(t + 2)) << 32)
                                       | (unsigned long long)__float_as_uint(h);
                __hip_atomic_store(&c2n[(size_t)w * H + rg * 16 + qlane],
                                   p64, __ATOMIC_RELAXED, __HIP_MEMORY_SCOPE_AGENT);
                r0 += h * mk;
            }
        }
        // NO S4: next iteration's tag check is the only consumer-side gate.
    }

    // ---- epilogue: dump rep registers (unique owner per (seq,unit))
    if (gate == 0)
        repg[(size_t)(seq_base + w) * H + rg * 16 + qlane] = r0;
}

// ---------------- final: rep mean + logits ----------------
__global__ __launch_bounds__(256) void lstm_final(
    const float* __restrict__ ws,
    const int* __restrict__ mask,
    const float* __restrict__ Wfc, const float* __restrict__ bfc,
    float* __restrict__ out)
{
    __shared__ float sred[256];
    __shared__ float srep[H];
    int s = blockIdx.x, tid = threadIdx.x;

    float dsum = 0.f;
    for (int i = tid; i < L; i += 256) dsum += (mask[(size_t)s * L + i] != 0) ? 1.f : 0.f;
    sred[tid] = dsum; __syncthreads();
    for (int off = 128; off > 0; off >>= 1) {
        if (tid < off) sred[tid] += sred[tid + off];
        __syncthreads();
    }
    float denom = fmaxf(sred[0], 1e-9f);
    __syncthreads();

    const float* repa = ws + OFF_REP + (size_t)s * H;
    for (int i = tid; i < H; i += 256) {
        float r = repa[i] / denom;
        srep[i] = r;
        out[128 + (size_t)s * H + i] = r;
    }
    __syncthreads();

    for (int c = 0; c < 2; ++c) {
        float d = 0.f;
        for (int i = tid; i < H; i += 256) d += srep[i] * Wfc[(size_t)c * H + i];
        sred[tid] = d; __syncthreads();
        for (int off = 128; off > 0; off >>= 1) {
            if (tid < off) sred[tid] += sred[tid + off];
            __syncthreads();
        }
        if (tid == 0) out[(size_t)s * 2 + c] = sred[0] + bfc[c];
        __syncthreads();
    }
}

// ---------------- host ----------------
extern "C" void kernel_launch(void* const* d_in, const int* in_sizes, int n_in,
                              void* d_out, int out_size, void* d_ws, size_t ws_size,
                              hipStream_t stream)
{
    const int*   x     = (const int*)d_in[0];
    const int*   mask  = (const int*)d_in[1];
    const float* embed = (const float*)d_in[2];
    const float* Wf = (const float*)d_in[3];  const float* bf = (const float*)d_in[4];
    const float* Wi = (const float*)d_in[5];  const float* bi = (const float*)d_in[6];
    const float* Wc = (const float*)d_in[7];  const float* bc = (const float*)d_in[8];
    const float* Wo = (const float*)d_in[9];  const float* bo = (const float*)d_in[10];
    const float* Wfc = (const float*)d_in[11]; const float* bfc = (const float*)d_in[12];
    float* out = (float*)d_out;
    float* ws  = (float*)d_ws;

    if (ws_size < WS_FLOATS * sizeof(float)) {
        return; // leave output poisoned so the failure mode is unambiguous
    }

    prep_weights<<<256, 256, 0, stream>>>(Wf, Wi, Wc, Wo, bf, bi, bc, bo, ws);
    lstm_persist<<<256, 512, 0, stream>>>(ws, x, mask, embed);
    lstm_final<<<64, 256, 0, stream>>>(ws, mask, Wfc, bfc, out);
}